// Round 4
// baseline (10380.925 us; speedup 1.0000x reference)
//
#include <hip/hip_runtime.h>
#include <math.h>

// RITS recurrent imputation. B=256, T=100, F=256, H=512.
// Round 4: round-3 structure with (a) fixed slab staging indexing (ull = 4
// ushorts!), (b) formally-correct flag-based release/acquire grid barrier
// (agent scope; no serialized RMW arrival, no __threadfence).
//   wgs 0-15:  x_h -> x_c -> z_h -> c_c chain in-wg (M=16, full width).
//   wgs 16-255: gates GEMM K=[m|hdec] part (K=768) in SEG1 (acc in VGPRs
//   across the barrier), + cc part (K=256) + fused LSTM epilogue in SEG2.

#define T_ 100
typedef unsigned short ushortT;
typedef unsigned long long ull;
typedef __attribute__((ext_vector_type(8))) short short8;
typedef __attribute__((ext_vector_type(4))) float f32x4;

#define AGENT __HIP_MEMORY_SCOPE_AGENT

// ---- workspace byte offsets ----
#define OB_HD0   0u          // bf16 hdec buf0 [256*512]
#define OB_HD1   262144u     // bf16 hdec buf1
#define OB_CCB   524288u     // bf16 c_c [256*256]
#define OB_GO    655360u     // u32 barrier broadcast (64B slot)
#define OB_LACC  655424u     // f32 loss accumulator (64B slot)
#define OB_DEN   655488u     // f32 [128] mask sums per t
#define OB_FLAGS 656000u     // u32 arrival flags, 256 x 64B
#define OB_BIASP 672384u     // f32 [2048] packed b_ih+b_hh
#define OB_BA    680576u     // bf16 W_hist [256,512]
#define OB_BF    942720u     // bf16 W_feat masked [256,256]
#define OB_BC    1073792u    // bf16 packed [2048,1024] = [Wih | Whh], row n=4j+g
#define OB_BTH   5268096u    // bf16 W_td_h [512,256]
#define OB_BCB   5530240u    // bf16 W_comb [256,512]
#define OB_GXM   5792384u    // bf16 [25600,512] = [gamma_x | m]
#define OB_MT    32006784u   // bf16 masks time-major [100,256,256]
#define OB_GH    45113984u   // bf16 gamma_h [25600,512]
#define OB_AL    71328384u   // bf16 alpha [25600,256] (dt scratch earlier)
// end 84,435,584 B (~80.5 MB)

__device__ __forceinline__ float sigm(float x) { return 1.0f / (1.0f + expf(-x)); }

__device__ __forceinline__ ushortT f2bf(float f) {
    union { float f; unsigned u; } v; v.f = f;
    unsigned r = v.u + 0x7fffu + ((v.u >> 16) & 1u);
    return (ushortT)(r >> 16);
}
__device__ __forceinline__ float bf2f(ushortT h) {
    union { unsigned u; float f; } v; v.u = ((unsigned)h) << 16; return v.f;
}

__device__ __forceinline__ void astore8(ushortT* p, ull v) {
    __hip_atomic_store((ull*)p, v, __ATOMIC_RELAXED, AGENT);   // write-through
}

// Flag-array barrier, agent-scope release/acquire (memory-model-correct):
// every wg release-stores its own 64B-padded flag (parallel writebacks),
// wg0 acquire-polls all flags then release-stores the go broadcast, others
// acquire-poll go. Each wg performs >=1 acquire per barrier -> local L1/L2
// invalidated before consuming remote data.
__device__ __forceinline__ void gsync(unsigned* flags, unsigned* go, int wg, unsigned ep) {
    __syncthreads();
    const int tid = threadIdx.x;
    if (wg == 0) {
        if (tid > 0) {
            while (__hip_atomic_load(&flags[tid * 16], __ATOMIC_ACQUIRE, AGENT) < ep)
                __builtin_amdgcn_s_sleep(1);
        }
        __syncthreads();
        if (tid == 0)
            __hip_atomic_store(go, ep, __ATOMIC_RELEASE, AGENT);
    } else {
        if (tid == 0) {
            __hip_atomic_store(&flags[wg * 16], ep, __ATOMIC_RELEASE, AGENT);
            while (__hip_atomic_load(go, __ATOMIC_ACQUIRE, AGENT) < ep)
                __builtin_amdgcn_s_sleep(1);
        }
        __syncthreads();
    }
}

// ---------------- prep ----------------

__global__ __launch_bounds__(256) void k_init(unsigned char* wsb) {
    unsigned i = blockIdx.x * 256u + threadIdx.x;
    if (i < 168096u) ((unsigned*)wsb)[i] = 0u;   // hd0,hd1,ccb,go,lacc,den,flags
}

__global__ __launch_bounds__(256) void k_prepw(const float* __restrict__ W_ih,
                                               const float* __restrict__ W_hh,
                                               const float* __restrict__ b_ih,
                                               const float* __restrict__ b_hh,
                                               const float* __restrict__ W_hist,
                                               const float* __restrict__ W_feat,
                                               const float* __restrict__ W_comb,
                                               const float* __restrict__ W_td_h,
                                               unsigned char* wsb) {
    ushortT* Bc  = (ushortT*)(wsb + OB_BC);
    ushortT* Ba  = (ushortT*)(wsb + OB_BA);
    ushortT* Bf  = (ushortT*)(wsb + OB_BF);
    ushortT* Bcb = (ushortT*)(wsb + OB_BCB);
    ushortT* Bth = (ushortT*)(wsb + OB_BTH);
    float* biasp = (float*)(wsb + OB_BIASP);
    int n = blockIdx.x, j = n >> 2, g = n & 3, src = g * 512 + j;
    for (int k = threadIdx.x; k < 512; k += 256) {
        Bc[(size_t)n * 1024 + k]       = f2bf(W_ih[(size_t)src * 512 + k]);
        Bc[(size_t)n * 1024 + 512 + k] = f2bf(W_hh[(size_t)src * 512 + k]);
        if (n < 256) {
            Ba[(size_t)n * 512 + k]  = f2bf(W_hist[(size_t)n * 512 + k]);
            Bcb[(size_t)n * 512 + k] = f2bf(W_comb[(size_t)n * 512 + k]);
            if (k < 256) Bf[n * 256 + k] = (k == n) ? (ushortT)0 : f2bf(W_feat[n * 256 + k]);
        }
        if (n < 512 && k < 256) Bth[n * 256 + k] = f2bf(W_td_h[n * 256 + k]);
    }
    if (threadIdx.x == 0) biasp[n] = b_ih[src] + b_hh[src];
}

// elementwise: dt (bf16 deltas), gxm=[gamma_x|m], mt (time-major masks), den
__global__ __launch_bounds__(256) void k_elem(const float* __restrict__ deltas,
                                              const float* __restrict__ masks,
                                              const float* __restrict__ Wtdx,
                                              const float* __restrict__ btdx,
                                              unsigned char* wsb) {
    ushortT* dt  = (ushortT*)(wsb + OB_AL);     // scratch; overwritten by al later
    ushortT* gxm = (ushortT*)(wsb + OB_GXM);
    ushortT* mt  = (ushortT*)(wsb + OB_MT);
    float* den   = (float*)(wsb + OB_DEN);
    int tid = threadIdx.x, lane = tid & 63;
    int row = blockIdx.x * 4 + (tid >> 6);              // 0..25599
    int b = row / 100, t = row - b * 100;
    int f0 = lane * 4;
    float4 d = *(const float4*)(deltas + (size_t)row * 256 + f0);
    float4 m = *(const float4*)(masks + (size_t)row * 256 + f0);
    union { ushortT s[4]; ull q; } p;
    p.s[0] = f2bf(d.x); p.s[1] = f2bf(d.y); p.s[2] = f2bf(d.z); p.s[3] = f2bf(d.w);
    *(ull*)(dt + (size_t)row * 256 + f0) = p.q;
    float gx0 = expf(-fmaxf(d.x * Wtdx[(size_t)(f0 + 0) * 257] + btdx[f0 + 0], 0.f));
    float gx1 = expf(-fmaxf(d.y * Wtdx[(size_t)(f0 + 1) * 257] + btdx[f0 + 1], 0.f));
    float gx2 = expf(-fmaxf(d.z * Wtdx[(size_t)(f0 + 2) * 257] + btdx[f0 + 2], 0.f));
    float gx3 = expf(-fmaxf(d.w * Wtdx[(size_t)(f0 + 3) * 257] + btdx[f0 + 3], 0.f));
    p.s[0] = f2bf(gx0); p.s[1] = f2bf(gx1); p.s[2] = f2bf(gx2); p.s[3] = f2bf(gx3);
    *(ull*)(gxm + (size_t)row * 512 + f0) = p.q;
    union { ushortT s[4]; ull q; } pm;
    pm.s[0] = f2bf(m.x); pm.s[1] = f2bf(m.y); pm.s[2] = f2bf(m.z); pm.s[3] = f2bf(m.w);
    *(ull*)(gxm + (size_t)row * 512 + 256 + f0) = pm.q;
    *(ull*)(mt + ((size_t)t * 256 + b) * 256 + f0) = pm.q;
    float s = m.x + m.y + m.z + m.w;
    for (int off = 32; off; off >>= 1) s += __shfl_down(s, off);
    if (lane == 0) atomicAdd(den + t, s);
}

// gamma_h = exp(-relu(dt @ W_td_h^T + b)) : [25600,512], K=256, bf16 MFMA
__global__ __launch_bounds__(256) void k_gemm_gh(const float* __restrict__ b_td_h,
                                                 unsigned char* wsb) {
    const ushortT* A  = (const ushortT*)(wsb + OB_AL);
    const ushortT* Bw = (const ushortT*)(wsb + OB_BTH);
    ushortT* gh = (ushortT*)(wsb + OB_GH);
    int tid = threadIdx.x, wave = tid >> 6, lane = tid & 63, quad = lane >> 4, l16 = lane & 15;
    int mb = blockIdx.x * 64, nb = blockIdx.y * 64;
    int r0 = mb + wave * 16;
    f32x4 acc[4] = {};
    const ushortT* arow = A + (size_t)(r0 + l16) * 256 + quad * 8;
    const ushortT* brow = Bw + (size_t)(nb + l16) * 256 + quad * 8;
    for (int kc = 0; kc < 8; ++kc) {
        short8 a = *(const short8*)(arow + kc * 32);
#pragma unroll
        for (int nt = 0; nt < 4; ++nt) {
            short8 b = *(const short8*)(brow + (size_t)nt * 16 * 256 + kc * 32);
            acc[nt] = __builtin_amdgcn_mfma_f32_16x16x32_bf16(a, b, acc[nt], 0, 0, 0);
        }
    }
#pragma unroll
    for (int nt = 0; nt < 4; ++nt) {
        int n = nb + nt * 16 + l16;
        float bias = b_td_h[n];
#pragma unroll
        for (int r4 = 0; r4 < 4; ++r4) {
            int row = r0 + quad * 4 + r4;
            float v = acc[nt][r4] + bias;
            gh[(size_t)row * 512 + n] = f2bf(expf(-fmaxf(v, 0.f)));
        }
    }
}

// alpha = sigmoid(gxm @ W_comb^T + b) : [25600,256], K=512, bf16 MFMA
__global__ __launch_bounds__(256) void k_gemm_al(const float* __restrict__ b_comb,
                                                 unsigned char* wsb) {
    const ushortT* A  = (const ushortT*)(wsb + OB_GXM);
    const ushortT* Bw = (const ushortT*)(wsb + OB_BCB);
    ushortT* al = (ushortT*)(wsb + OB_AL);
    int tid = threadIdx.x, wave = tid >> 6, lane = tid & 63, quad = lane >> 4, l16 = lane & 15;
    int mb = blockIdx.x * 64, nb = blockIdx.y * 64;
    int r0 = mb + wave * 16;
    f32x4 acc[4] = {};
    const ushortT* arow = A + (size_t)(r0 + l16) * 512 + quad * 8;
    const ushortT* brow = Bw + (size_t)(nb + l16) * 512 + quad * 8;
    for (int kc = 0; kc < 16; ++kc) {
        short8 a = *(const short8*)(arow + kc * 32);
#pragma unroll
        for (int nt = 0; nt < 4; ++nt) {
            short8 b = *(const short8*)(brow + (size_t)nt * 16 * 512 + kc * 32);
            acc[nt] = __builtin_amdgcn_mfma_f32_16x16x32_bf16(a, b, acc[nt], 0, 0, 0);
        }
    }
#pragma unroll
    for (int nt = 0; nt < 4; ++nt) {
        int n = nb + nt * 16 + l16;
        float bias = b_comb[n];
#pragma unroll
        for (int r4 = 0; r4 < 4; ++r4) {
            int row = r0 + quad * 4 + r4;
            al[(size_t)row * 256 + n] = f2bf(sigm(acc[nt][r4] + bias));
        }
    }
}

// ---------------- persistent kernel ----------------

__global__ __launch_bounds__(256, 1) void k_persist(const float* __restrict__ values,
                                                    const float* __restrict__ masks,
                                                    const float* __restrict__ b_hist,
                                                    const float* __restrict__ b_feat,
                                                    float* __restrict__ out,
                                                    unsigned char* __restrict__ wsb) {
    ushortT* hdbuf0 = (ushortT*)(wsb + OB_HD0);
    ushortT* hdbuf1 = (ushortT*)(wsb + OB_HD1);
    ushortT* ccb = (ushortT*)(wsb + OB_CCB);
    unsigned* go = (unsigned*)(wsb + OB_GO);
    unsigned* flags = (unsigned*)(wsb + OB_FLAGS);
    float* lossAcc = (float*)(wsb + OB_LACC);
    const float* den = (const float*)(wsb + OB_DEN);
    const float* biasp = (const float*)(wsb + OB_BIASP);
    const ushortT* Ba = (const ushortT*)(wsb + OB_BA);
    const ushortT* Bf = (const ushortT*)(wsb + OB_BF);
    const ushortT* Bc = (const ushortT*)(wsb + OB_BC);
    const ushortT* mt = (const ushortT*)(wsb + OB_MT);
    const ushortT* gh = (const ushortT*)(wsb + OB_GH);
    const ushortT* al = (const ushortT*)(wsb + OB_AL);

    __shared__ ushortT slab[32 * 520];   // 33280 B: C wgs hd/cc staging
    __shared__ ushortT xcL[16 * 264];    //  8448 B: AB wgs x_c / c_c staging
    __shared__ float scr[4][256];        //  4096 B: per-wave gate transpose
    __shared__ ushortT hdS[4][64];       //   512 B: per-wave hd staging
    __shared__ float red[256];

    const int wg = blockIdx.x, tid = threadIdx.x;
    const int wave = tid >> 6, lane = tid & 63, quad = lane >> 4, l16 = lane & 15;
    const bool isAB = (wg < 16);
    const int ntile = isAB ? 0 : ((wg < 32) ? 2 : 1);
    const int rw = wave & 1, cw = wave >> 1;

    f32x4 accC[2][2];
    float c_reg[2][2] = {{0.f, 0.f}, {0.f, 0.f}};
    float lacc = 0.f;

    unsigned epoch = 0;
    for (int t = 0; t < T_; ++t) {
        const ushortT* hdA = (t & 1) ? hdbuf1 : hdbuf0;
        ushortT* hdW = (t & 1) ? hdbuf0 : hdbuf1;
        const ushortT* mtT = mt + (size_t)t * 65536;

        // ================= SEG 1 =================
        if (isAB) {
            const int r0 = wg * 16;
            // phase A: x_h[16,256] = hdec @ W_hist^T (K=512)
            f32x4 accA[4] = {};
            const ushortT* hrow = hdA + (size_t)(r0 + l16) * 512 + quad * 8;
            const ushortT* BaW = Ba + (size_t)(wave * 64 + l16) * 512 + quad * 8;
#pragma unroll 4
            for (int kc = 0; kc < 16; ++kc) {
                short8 a = *(const short8*)(hrow + kc * 32);
#pragma unroll
                for (int nt = 0; nt < 4; ++nt) {
                    short8 b = *(const short8*)(BaW + (size_t)nt * 16 * 512 + kc * 32);
                    accA[nt] = __builtin_amdgcn_mfma_f32_16x16x32_bf16(a, b, accA[nt], 0, 0, 0);
                }
            }
            float xhreg[16];
#pragma unroll
            for (int nt = 0; nt < 4; ++nt) {
                int n = wave * 64 + nt * 16 + l16;
                float bh = b_hist[n];
#pragma unroll
                for (int r4 = 0; r4 < 4; ++r4) {
                    int rr = quad * 4 + r4;
                    float v = accA[nt][r4] + bh;
                    xhreg[nt * 4 + r4] = v;
                    size_t idx = ((size_t)(r0 + rr) * T_ + t) * 256 + n;
                    float x = values[idx], m = masks[idx];
                    xcL[rr * 264 + n] = f2bf(v + m * (x - v));
                }
            }
            __syncthreads();
            // phase B: z_h = x_c @ Wf^T (K=256)
            f32x4 accB[4] = {};
#pragma unroll 4
            for (int kc = 0; kc < 8; ++kc) {
                short8 a = *(const short8*)&xcL[l16 * 264 + kc * 32 + quad * 8];
#pragma unroll
                for (int nt = 0; nt < 4; ++nt) {
                    short8 b = *(const short8*)(Bf + (size_t)(wave * 64 + nt * 16 + l16) * 256 + kc * 32 + quad * 8);
                    accB[nt] = __builtin_amdgcn_mfma_f32_16x16x32_bf16(a, b, accB[nt], 0, 0, 0);
                }
            }
            float invd = 1.0f / (den[t] + 1e-9f);
            __syncthreads();           // xcL about to be overwritten with c_c
#pragma unroll
            for (int nt = 0; nt < 4; ++nt) {
                int n = wave * 64 + nt * 16 + l16;
                float bfv = b_feat[n];
#pragma unroll
                for (int r4 = 0; r4 < 4; ++r4) {
                    int rr = quad * 4 + r4;
                    size_t idx = ((size_t)(r0 + rr) * T_ + t) * 256 + n;
                    float z = fmaxf(accB[nt][r4] + bfv, 0.f);
                    float a_ = bf2f(al[idx]);
                    float xh = xhreg[nt * 4 + r4];
                    float ch = xh + a_ * (z - xh);
                    float x = values[idx], m = masks[idx];
                    float ccv = ch + m * (x - ch);
                    out[idx] = ccv;                        // imputed[:,t,:] == c_c
                    xcL[rr * 264 + n] = f2bf(ccv);
                    lacc += (fabsf(xh - x) + fabsf(z - x) + fabsf(ch - x)) * (m * invd);
                }
            }
            __syncthreads();
            // c_c -> ccb, write-through. 16 rows x 64 ull (ull = 4 ushorts).
            for (int i = tid; i < 1024; i += 256) {
                int rr = i >> 6, c4 = i & 63;
                ull q = *(const ull*)&xcL[rr * 264 + c4 * 4];
                astore8(ccb + (size_t)(r0 + rr) * 256 + c4 * 4, q);
            }
        } else {
            // gates partial: K = [m(256) | hdec(512)]
            for (int it = 0; it < ntile; ++it) {
                int tau = (wg - 16) + it * 240;
                int mblk = tau >> 5, n0 = (tau & 31) * 64;
                int r0g = mblk * 32;
                if (it) __syncthreads();
                // hdec slab: 32 rows x 512 ushorts; 16B chunks: 64/row -> 2048
                for (int i = tid; i < 2048; i += 256) {
                    int rr = i >> 6, c16 = i & 63;
                    short8 v = *(const short8*)(hdA + (size_t)(r0g + rr) * 512 + c16 * 8);
                    *(short8*)&slab[rr * 520 + c16 * 8] = v;
                }
                __syncthreads();
                f32x4 a0 = {}, a1 = {};
                const ushortT* Brow0 = Bc + (size_t)(n0 + cw * 32 + l16) * 1024;
                const ushortT* Brow1 = Brow0 + (size_t)16 * 1024;
                const ushortT* mrow = mtT + (size_t)(r0g + rw * 16 + l16) * 256 + quad * 8;
#pragma unroll 4
                for (int kc = 0; kc < 8; ++kc) {
                    short8 a = *(const short8*)(mrow + kc * 32);
                    short8 b0 = *(const short8*)(Brow0 + 256 + kc * 32 + quad * 8);
                    short8 b1 = *(const short8*)(Brow1 + 256 + kc * 32 + quad * 8);
                    a0 = __builtin_amdgcn_mfma_f32_16x16x32_bf16(a, b0, a0, 0, 0, 0);
                    a1 = __builtin_amdgcn_mfma_f32_16x16x32_bf16(a, b1, a1, 0, 0, 0);
                }
                const ushortT* srow = &slab[(rw * 16 + l16) * 520 + quad * 8];
#pragma unroll 4
                for (int kc = 0; kc < 16; ++kc) {
                    short8 a = *(const short8*)(srow + kc * 32);
                    short8 b0 = *(const short8*)(Brow0 + 512 + kc * 32 + quad * 8);
                    short8 b1 = *(const short8*)(Brow1 + 512 + kc * 32 + quad * 8);
                    a0 = __builtin_amdgcn_mfma_f32_16x16x32_bf16(a, b0, a0, 0, 0, 0);
                    a1 = __builtin_amdgcn_mfma_f32_16x16x32_bf16(a, b1, a1, 0, 0, 0);
                }
                accC[it][0] = a0;
                accC[it][1] = a1;
            }
        }
        gsync(flags, go, wg, ++epoch);

        // ================= SEG 2 =================
        if (!isAB) {
            for (int it = 0; it < ntile; ++it) {
                int tau = (wg - 16) + it * 240;
                int mblk = tau >> 5, n0 = (tau & 31) * 64;
                int r0g = mblk * 32;
                __syncthreads();
                // cc slab: 32 rows x 256 ushorts; 16B chunks: 32/row -> 1024
                for (int i = tid; i < 1024; i += 256) {
                    int rr = i >> 5, c16 = i & 31;
                    short8 v = *(const short8*)(ccb + (size_t)(r0g + rr) * 256 + c16 * 8);
                    *(short8*)&slab[rr * 264 + c16 * 8] = v;
                }
                __syncthreads();
                f32x4 a0 = accC[it][0], a1 = accC[it][1];
                const ushortT* Brow0 = Bc + (size_t)(n0 + cw * 32 + l16) * 1024;
                const ushortT* Brow1 = Brow0 + (size_t)16 * 1024;
                const ushortT* srow = &slab[(rw * 16 + l16) * 264 + quad * 8];
#pragma unroll 4
                for (int kc = 0; kc < 8; ++kc) {
                    short8 a = *(const short8*)(srow + kc * 32);
                    short8 b0 = *(const short8*)(Brow0 + kc * 32 + quad * 8);
                    short8 b1 = *(const short8*)(Brow1 + kc * 32 + quad * 8);
                    a0 = __builtin_amdgcn_mfma_f32_16x16x32_bf16(a, b0, a0, 0, 0, 0);
                    a1 = __builtin_amdgcn_mfma_f32_16x16x32_bf16(a, b1, a1, 0, 0, 0);
                }
                float bp0 = biasp[n0 + cw * 32 + l16];
                float bp1 = biasp[n0 + cw * 32 + 16 + l16];
#pragma unroll
                for (int nt2 = 0; nt2 < 2; ++nt2) {
                    f32x4 acc = nt2 ? a1 : a0;
                    float bp = nt2 ? bp1 : bp0;
#pragma unroll
                    for (int r4 = 0; r4 < 4; ++r4)
                        scr[wave][(quad * 4 + r4) * 16 + l16] = acc[r4] + bp;
                    int rloc = lane >> 2, u = lane & 3;
                    float gi = scr[wave][rloc * 16 + u * 4 + 0];
                    float gf = scr[wave][rloc * 16 + u * 4 + 1];
                    float gg = scr[wave][rloc * 16 + u * 4 + 2];
                    float go_ = scr[wave][rloc * 16 + u * 4 + 3];
                    int b_ = r0g + rw * 16 + rloc;
                    int j = ((n0 + cw * 32 + nt2 * 16) >> 2) + u;
                    float c = c_reg[it][nt2];
                    float cn = sigm(gf) * c + sigm(gi) * tanhf(gg);
                    float hn = sigm(go_) * tanhf(cn);
                    c_reg[it][nt2] = cn;
                    if (t < T_ - 1) {
                        float gv = bf2f(gh[((size_t)b_ * T_ + t + 1) * 512 + j]);
                        hdS[wave][rloc * 4 + u] = f2bf(hn * gv);
                        if (u == 0) {
                            ull q = *(const ull*)&hdS[wave][rloc * 4];
                            astore8(hdW + (size_t)b_ * 512 + ((n0 + cw * 32 + nt2 * 16) >> 2), q);
                        }
                    } else {
                        out[6553600 + (size_t)b_ * 512 + j] = hn;   // final h
                    }
                }
            }
        }
        gsync(flags, go, wg, ++epoch);
    }

    // ---- loss finalize ----
    if (isAB) {
        red[tid] = lacc;
        __syncthreads();
        for (int s = 128; s > 0; s >>= 1) {
            if (tid < s) red[tid] += red[tid + s];
            __syncthreads();
        }
        if (tid == 0) atomicAdd(lossAcc, red[0]);
    }
    gsync(flags, go, wg, ++epoch);
    if (wg == 0 && tid == 0) out[6684672] = lossAcc[0] / 300.0f;
}

extern "C" void kernel_launch(void* const* d_in, const int* in_sizes, int n_in,
                              void* d_out, int out_size, void* d_ws, size_t ws_size,
                              hipStream_t stream) {
    (void)in_sizes; (void)n_in; (void)out_size; (void)ws_size;
    const float* values = (const float*)d_in[0];
    const float* masks  = (const float*)d_in[1];
    const float* deltas = (const float*)d_in[2];
    const float* W_td_h = (const float*)d_in[3];
    const float* b_td_h = (const float*)d_in[4];
    const float* W_td_x = (const float*)d_in[5];
    const float* b_td_x = (const float*)d_in[6];
    const float* W_hist = (const float*)d_in[7];
    const float* b_hist = (const float*)d_in[8];
    const float* W_feat = (const float*)d_in[9];
    const float* b_feat = (const float*)d_in[10];
    const float* W_comb = (const float*)d_in[11];
    const float* b_comb = (const float*)d_in[12];
    const float* W_ih   = (const float*)d_in[13];
    const float* W_hh   = (const float*)d_in[14];
    const float* b_ih   = (const float*)d_in[15];
    const float* b_hh   = (const float*)d_in[16];

    unsigned char* wsb = (unsigned char*)d_ws;
    float* out = (float*)d_out;

    k_init<<<657, 256, 0, stream>>>(wsb);
    k_prepw<<<2048, 256, 0, stream>>>(W_ih, W_hh, b_ih, b_hh, W_hist, W_feat, W_comb, W_td_h, wsb);
    k_elem<<<6400, 256, 0, stream>>>(deltas, masks, W_td_x, b_td_x, wsb);
    k_gemm_gh<<<dim3(400, 8), 256, 0, stream>>>(b_td_h, wsb);
    k_gemm_al<<<dim3(400, 4), 256, 0, stream>>>(b_comb, wsb);
    k_persist<<<256, 256, 0, stream>>>(values, masks, b_hist, b_feat, out, wsb);
}